// Round 6
// baseline (118.879 us; speedup 1.0000x reference)
//
#include <hip/hip_runtime.h>

// Bahdanau additive attention: B=8, TE=512, TD=256, H=256, fp32.
//   We = enc @ W_a; Uh = dec @ U_a
//   e[b,j,i] = softmax_i( sum_h V[h]*tanh(We[b,i,h]+Uh[b,j,h]) )
//   c[b,j,h] = sum_i e[b,j,i]*enc[b,i,h]
// d_out = [c (B*TD*H)] ++ [e (B*TD*TE)]
//
// R14 (this round): the COMBO never tested. R12 = {LDS operands, 16 w/CU}:
// busy 49->63 but +issue, stall remained. R13 = {SMEM operands, 32 w/CU}:
// stall remained (per-CU scalar-cache serialization is occupancy-proof).
// Now: k_energy with LDS-staged u/v (zero SMEM in loop, one barrier) AND
// 32 waves/CU (h-split x2, 2048 blocks, launch_bounds(256,8)). Single
// delta vs R13. If this still lands ~30us -> phase A is issue-bound at 2x
// the instruction model; pivot to instruction-count reduction.
// R13 keeps: h-split partial energies -> 8MB ws; k_soft combines halves.
// R9 keeps: split-bf16 MFMA k_pre (384 blocks), k_tw weight transpose.
// R8 keeps: 4-way rcp batching. R7 keeps: XCD swizzle, W4 layout.

#define BB 8
#define TE 512
#define TD 256
#define HH 256

#define EXP2F(x) __builtin_amdgcn_exp2f(x)
#define RCPF(x)  __builtin_amdgcn_rcpf(x)
#define KSCALE   2.8853900817779268f    // 2*log2(e)
#define NSC      (-2.8853900817779268f) // -2*log2(e)

typedef __attribute__((ext_vector_type(8))) short short8_t;  // 8 bf16 = 4 VGPR
typedef __attribute__((ext_vector_type(4))) float f32x4;     // MFMA acc

__device__ __forceinline__ unsigned short f2bf(float x) {
    unsigned int u = __float_as_uint(x);
    return (unsigned short)((u + 0x7FFFu + ((u >> 16) & 1u)) >> 16);  // RNE
}
__device__ __forceinline__ float bf2f(unsigned short h) {
    return __uint_as_float(((unsigned int)h) << 16);
}

// ---------------------------------------------------------------------------
// k_tw: one-shot transpose+split of the weights.
//   Wt[s][h][k] (bf16 hi/lo) = W_s[k][h],  s=0: Wa (enc), s=1: Ua (dec).
// 32 blocks x 256 threads, 64x64 tiles via LDS.
// ---------------------------------------------------------------------------
__global__ __launch_bounds__(256) void k_tw(
    const float* __restrict__ Wa, const float* __restrict__ Ua,
    unsigned short* __restrict__ Wth, unsigned short* __restrict__ Wtl)
{
    const int t    = threadIdx.x;
    const int s    = blockIdx.x >> 4;
    const int tile = blockIdx.x & 15;
    const int tk   = (tile >> 2) * 64;
    const int th   = (tile & 3) * 64;
    const float* W = s ? Ua : Wa;

    __shared__ float Ls[64][65];
    const int kr = t >> 4;          // 0..15
    const int hc = (t & 15) * 4;    // 0..60
    #pragma unroll
    for (int r = 0; r < 4; r++) {
        float4 v = *(const float4*)(W + (size_t)(tk + kr + 16 * r) * HH + th + hc);
        Ls[kr + 16 * r][hc + 0] = v.x; Ls[kr + 16 * r][hc + 1] = v.y;
        Ls[kr + 16 * r][hc + 2] = v.z; Ls[kr + 16 * r][hc + 3] = v.w;
    }
    __syncthreads();
    const int hr  = t >> 4;
    const int kc4 = (t & 15) * 4;
    #pragma unroll
    for (int r = 0; r < 4; r++) {
        const int hl = hr + 16 * r;
        float f0 = Ls[kc4 + 0][hl], f1 = Ls[kc4 + 1][hl];
        float f2 = Ls[kc4 + 2][hl], f3 = Ls[kc4 + 3][hl];
        ushort4 hi, lo;
        hi.x = f2bf(f0); lo.x = f2bf(f0 - bf2f(hi.x));
        hi.y = f2bf(f1); lo.y = f2bf(f1 - bf2f(hi.y));
        hi.z = f2bf(f2); lo.z = f2bf(f2 - bf2f(hi.z));
        hi.w = f2bf(f3); lo.w = f2bf(f3 - bf2f(hi.w));
        const size_t o = ((size_t)(s * 256 + th + hl)) * 256 + tk + kc4;
        *(ushort4*)(Wth + o) = hi;
        *(ushort4*)(Wtl + o) = lo;
    }
}

// ---------------------------------------------------------------------------
// k_pre (R9/R11 version): split-bf16 MFMA GEMM over X = [enc; dec], D[h][i].
// Tile: 64h x 64i, 384 blocks, 4 waves, wave -> 32x32 (2x2 frags of 16x16),
// K-chunks of 32, reg-prefetch of next chunk. Layouts (m89-verified):
//   A/B frags: row/col = l&15, k-octet = (l>>4)*8; D: col=l&15, row=(l>>4)*4+reg.
// ---------------------------------------------------------------------------
__global__ __launch_bounds__(256) void k_pre(
    const float* __restrict__ enc, const float* __restrict__ dec,
    const unsigned short* __restrict__ Wth, const unsigned short* __restrict__ Wtl,
    float* __restrict__ W4, float* __restrict__ Uhe)
{
    const int t  = threadIdx.x;
    const int it = blockIdx.x >> 2;       // 0..95  (i-tile)
    const int ht = blockIdx.x & 3;        // 0..3   (h-tile)
    const int i0 = it * 64;
    const int h0 = ht * 64;
    const bool is_enc = (i0 < BB * TE);   // < 4096
    const float* X = is_enc ? (enc + (size_t)i0 * HH)
                            : (dec + (size_t)(i0 - BB * TE) * HH);
    const int s = is_enc ? 0 : 1;
    const unsigned short* Ah = Wth + ((size_t)(s * 256 + h0)) * 256;
    const unsigned short* Al = Wtl + ((size_t)(s * 256 + h0)) * 256;

    __shared__ unsigned short At_h[64][40], At_l[64][40];
    __shared__ unsigned short Xs_h[64][40], Xs_l[64][40];

    const int sr = t >> 2;                // staging row 0..63
    const int sq = (t & 3) * 8;           // staging k-octet

    const int wv = t >> 6, l = t & 63;
    const int wh = (wv & 1) * 32;
    const int wi = (wv >> 1) * 32;
    const int fr = l & 15;
    const int fk = (l >> 4) * 8;
    const int rq = l >> 4;                // D row-quad

    f32x4 acc[2][2];
    #pragma unroll
    for (int a0 = 0; a0 < 2; a0++)
        #pragma unroll
        for (int a1 = 0; a1 < 2; a1++)
            acc[a0][a1] = (f32x4){0.f, 0.f, 0.f, 0.f};

    short8_t aH = *(const short8_t*)(Ah + (size_t)sr * 256 + sq);
    short8_t aL = *(const short8_t*)(Al + (size_t)sr * 256 + sq);
    float4   x0 = *(const float4*)(X + (size_t)sr * HH + sq);
    float4   x1 = *(const float4*)(X + (size_t)sr * HH + sq + 4);

    #pragma unroll
    for (int c = 0; c < 8; c++) {
        short8_t xh, xl;
        {
            unsigned short h;
            h = f2bf(x0.x); xh[0] = (short)h; xl[0] = (short)f2bf(x0.x - bf2f(h));
            h = f2bf(x0.y); xh[1] = (short)h; xl[1] = (short)f2bf(x0.y - bf2f(h));
            h = f2bf(x0.z); xh[2] = (short)h; xl[2] = (short)f2bf(x0.z - bf2f(h));
            h = f2bf(x0.w); xh[3] = (short)h; xl[3] = (short)f2bf(x0.w - bf2f(h));
            h = f2bf(x1.x); xh[4] = (short)h; xl[4] = (short)f2bf(x1.x - bf2f(h));
            h = f2bf(x1.y); xh[5] = (short)h; xl[5] = (short)f2bf(x1.y - bf2f(h));
            h = f2bf(x1.z); xh[6] = (short)h; xl[6] = (short)f2bf(x1.z - bf2f(h));
            h = f2bf(x1.w); xh[7] = (short)h; xl[7] = (short)f2bf(x1.w - bf2f(h));
        }
        __syncthreads();
        *(short8_t*)&At_h[sr][sq] = aH;
        *(short8_t*)&At_l[sr][sq] = aL;
        *(short8_t*)&Xs_h[sr][sq] = xh;
        *(short8_t*)&Xs_l[sr][sq] = xl;
        if (c < 7) {
            const int kc = (c + 1) * 32;
            aH = *(const short8_t*)(Ah + (size_t)sr * 256 + kc + sq);
            aL = *(const short8_t*)(Al + (size_t)sr * 256 + kc + sq);
            x0 = *(const float4*)(X + (size_t)sr * HH + kc + sq);
            x1 = *(const float4*)(X + (size_t)sr * HH + kc + sq + 4);
        }
        __syncthreads();
        #pragma unroll
        for (int fm = 0; fm < 2; fm++) {
            short8_t a_h = *(const short8_t*)&At_h[wh + 16 * fm + fr][fk];
            short8_t a_l = *(const short8_t*)&At_l[wh + 16 * fm + fr][fk];
            #pragma unroll
            for (int fn = 0; fn < 2; fn++) {
                short8_t b_h = *(const short8_t*)&Xs_h[wi + 16 * fn + fr][fk];
                short8_t b_l = *(const short8_t*)&Xs_l[wi + 16 * fn + fr][fk];
                acc[fm][fn] = __builtin_amdgcn_mfma_f32_16x16x32_bf16(a_h, b_h, acc[fm][fn], 0, 0, 0);
                acc[fm][fn] = __builtin_amdgcn_mfma_f32_16x16x32_bf16(a_h, b_l, acc[fm][fn], 0, 0, 0);
                acc[fm][fn] = __builtin_amdgcn_mfma_f32_16x16x32_bf16(a_l, b_h, acc[fm][fn], 0, 0, 0);
            }
        }
    }

    #pragma unroll
    for (int fm = 0; fm < 2; fm++) {
        #pragma unroll
        for (int fn = 0; fn < 2; fn++) {
            f32x4 v = acc[fm][fn];
            float4 o;
            o.x = EXP2F(v[0] * KSCALE);
            o.y = EXP2F(v[1] * KSCALE);
            o.z = EXP2F(v[2] * KSCALE);
            o.w = EXP2F(v[3] * KSCALE);
            const int ig = i0 + wi + 16 * fn + fr;      // global concat row
            const int hb = h0 + wh + 16 * fm + rq * 4;  // 4 consecutive h
            if (is_enc) {
                const int b  = ig >> 9;                 // 512 enc rows per batch
                const int ib = ig & 511;
                const int hq = hb >> 2;
                *(float4*)(W4 + (((size_t)b * 64 + hq) * TE + ib) * 4) = o;
            } else {
                const int j = ig - BB * TE;             // global dec row
                *(float4*)(Uhe + (size_t)j * HH + hb) = o;
            }
        }
    }
}

// ---------------------------------------------------------------------------
// k_energy (R14): LDS-operand + full-occupancy partial energies.
// Block decode: b = bid&7 (XCD-local), jg = (bid>>3)&63, hs = (bid>>9)&1
// (h-half), ih = bid>>10 (i-half). 2048 blocks x 256 thr = 8 blocks/CU
// = 32 waves/CU; launch_bounds(256,8) pins VGPR<=64.
// u (4 j-rows x 128 h) + v (128) staged to LDS once (2.5 KB, one barrier);
// inner loop = {1 VMEM w4 + 5 ds_read_b128 broadcasts + 56 VALU + 4 rcp},
// ZERO scalar-memory ops, no barriers. Writes RAW partial sums to
// E[hs][jj][i]; k_soft combines. Same values/order as R13 -> bit-identical.
// ---------------------------------------------------------------------------
__global__ __launch_bounds__(256, 8) void k_energy(
    const float* __restrict__ W4, const float* __restrict__ Uhe,
    const float* __restrict__ Va, float* __restrict__ E)
{
    const int t   = threadIdx.x;
    const int bid = blockIdx.x;
    const int b   = bid & 7;                 // XCD-local batch
    const int jg  = (bid >> 3) & 63;         // j-group
    const int hs  = (bid >> 9) & 1;          // h-half
    const int ih  = bid >> 10;               // i-half
    const int jj0 = b * TD + jg * 4;
    const int i   = ih * 256 + t;

    __shared__ float sU[4][128];   // 2 KB: the block's 4 Uhe half-rows
    __shared__ float sV[128];      // 0.5 KB: Va half

    // stage u+v: 640 floats = 160 float4 (threads 0..159)
    if (t < 160) {
        const int idx = t * 4;
        if (idx < 512) {
            float4 v = *(const float4*)(Uhe + (size_t)(jj0 + (idx >> 7)) * HH
                                        + hs * 128 + (idx & 127));
            *(float4*)&sU[idx >> 7][idx & 127] = v;
        } else {
            float4 v = *(const float4*)(Va + hs * 128 + (idx - 512));
            *(float4*)&sV[idx - 512] = v;
        }
    }
    __syncthreads();

    const float* wp = W4 + ((size_t)(b * 64 + hs * 32) * TE + i) * 4;

    float a0 = 0.f, a1 = 0.f, a2 = 0.f, a3 = 0.f;

    // 4-way batched reciprocal:
    //   sum_k v_k/A_k = (nAB*dCD + nCD*dAB) / (dAB*dCD)
#define QSTEP(ACC, U)                                                     \
    {                                                                     \
        float A_ = fmaf(w4.x, (U).x, 1.f);                                \
        float B_ = fmaf(w4.y, (U).y, 1.f);                                \
        float C_ = fmaf(w4.z, (U).z, 1.f);                                \
        float D_ = fmaf(w4.w, (U).w, 1.f);                                \
        float dAB = A_ * B_, dCD = C_ * D_;                               \
        float nAB = fmaf(v4.x, B_, v4.y * A_);                            \
        float nCD = fmaf(v4.z, D_, v4.w * C_);                            \
        float num = fmaf(nAB, dCD, nCD * dAB);                            \
        ACC = fmaf(num, RCPF(dAB * dCD), ACC);                            \
    }

    #pragma unroll 2
    for (int q = 0; q < 32; q++) {
        float4 w4 = *(const float4*)(wp + (size_t)q * TE * 4);
        float4 v4 = *(const float4*)&sV[4 * q];
        float4 u0 = *(const float4*)&sU[0][4 * q];
        float4 u1 = *(const float4*)&sU[1][4 * q];
        float4 u2 = *(const float4*)&sU[2][4 * q];
        float4 u3 = *(const float4*)&sU[3][4 * q];
        QSTEP(a0, u0)
        QSTEP(a1, u1)
        QSTEP(a2, u2)
        QSTEP(a3, u3)
    }
#undef QSTEP

    float* ep = E + (size_t)hs * (BB * TD * TE) + (size_t)jj0 * TE + i;
    ep[0]      = a0;
    ep[TE]     = a1;
    ep[2 * TE] = a2;
    ep[3 * TE] = a3;
}

// ---------------------------------------------------------------------------
// k_soft (R13): combine the two E halves (sP = NSC*(e0+e1)), then softmax +
// phase B. 512 threads = 8 waves; block owns 4 consecutive j's of ONE
// batch, batch = blockIdx&7 (XCD-local).
// ---------------------------------------------------------------------------
__global__ __launch_bounds__(512) void k_soft(
    const float* __restrict__ enc, const float* __restrict__ E,
    float* __restrict__ out_c, float* __restrict__ out_e)
{
    const int t  = threadIdx.x;
    const int wv = t >> 6, lane = t & 63;
    const int b   = blockIdx.x & 7;           // XCD-local batch
    const int j0  = (blockIdx.x >> 3) * 4;    // 64 j-groups per batch
    const int jj0 = b * TD + j0;              // block-uniform

    __shared__ float sP[4][TE];      // 8 KB: energies -> probabilities
    __shared__ float sR[8][4][HH];   // 32 KB: phase-B partials

    // combine halves: 2048 floats, one float4 per thread
    {
        const float* e0 = E + (size_t)jj0 * TE;
        const float* e1 = E + (size_t)(BB * TD * TE) + (size_t)jj0 * TE;
        float4 v0 = *(const float4*)(e0 + t * 4);
        float4 v1 = *(const float4*)(e1 + t * 4);
        float4 s;
        s.x = NSC * (v0.x + v1.x);
        s.y = NSC * (v0.y + v1.y);
        s.z = NSC * (v0.z + v1.z);
        s.w = NSC * (v0.w + v1.w);
        *(float4*)&((float*)sP)[t * 4] = s;
    }
    __syncthreads();

    // ---- softmax: wave w in 0..3 handles j0+w ----------------------------
    if (wv < 4) {
        float ev[8];
        float m = -3.0e38f;
        #pragma unroll
        for (int k = 0; k < 8; k++) {
            ev[k] = sP[wv][lane + 64 * k];
            m = fmaxf(m, ev[k]);
        }
        #pragma unroll
        for (int off = 32; off; off >>= 1) m = fmaxf(m, __shfl_xor(m, off, 64));
        float s = 0.f;
        #pragma unroll
        for (int k = 0; k < 8; k++) { ev[k] = EXP2F(ev[k] - m); s += ev[k]; }
        #pragma unroll
        for (int off = 32; off; off >>= 1) s += __shfl_xor(s, off, 64);
        float rs = RCPF(s);
        float* oe = out_e + (size_t)(jj0 + wv) * TE;
        #pragma unroll
        for (int k = 0; k < 8; k++) {
            float p = ev[k] * rs;
            sP[wv][lane + 64 * k] = p;
            oe[lane + 64 * k] = p;
        }
    }
    __syncthreads();

    // ---- Phase B: wave w -> i in [64w, 64w+64), all 4 j ------------------
    const int ib = wv << 6;
    const float* eb = enc + ((size_t)b * TE + ib) * HH + 4 * lane;
    float4 c0 = {0,0,0,0}, c1 = {0,0,0,0}, c2 = {0,0,0,0}, c3 = {0,0,0,0};
    #pragma unroll 2
    for (int k = 0; k < 64; k++) {
        float p0 = sP[0][ib + k];   // uniform broadcasts
        float p1 = sP[1][ib + k];
        float p2 = sP[2][ib + k];
        float p3 = sP[3][ib + k];
        float4 q = *(const float4*)(eb + (size_t)k * HH);
        c0.x = fmaf(p0, q.x, c0.x); c0.y = fmaf(p0, q.y, c0.y);
        c0.z = fmaf(p0, q.z, c0.z); c0.w = fmaf(p0, q.w, c0.w);
        c1.x = fmaf(p1, q.x, c1.x); c1.y = fmaf(p1, q.y, c1.y);
        c1.z = fmaf(p1, q.z, c1.z); c1.w = fmaf(p1, q.w, c1.w);
        c2.x = fmaf(p2, q.x, c2.x); c2.y = fmaf(p2, q.y, c2.y);
        c2.z = fmaf(p2, q.z, c2.z); c2.w = fmaf(p2, q.w, c2.w);
        c3.x = fmaf(p3, q.x, c3.x); c3.y = fmaf(p3, q.y, c3.y);
        c3.z = fmaf(p3, q.z, c3.z); c3.w = fmaf(p3, q.w, c3.w);
    }
    *(float4*)&sR[wv][0][4 * lane] = c0;
    *(float4*)&sR[wv][1][4 * lane] = c1;
    *(float4*)&sR[wv][2][4 * lane] = c2;
    *(float4*)&sR[wv][3][4 * lane] = c3;
    __syncthreads();

    // ---- final reduce: wave w -> (j = w&3, h-half = w>>2) ----------------
    {
        const int jr = wv & 3;
        const int h2 = (wv >> 2) * 128 + 2 * lane;
        float sx = 0.f, sy = 0.f;
        #pragma unroll
        for (int ww = 0; ww < 8; ww++) {
            float2 tv = *(const float2*)&sR[ww][jr][h2];
            sx += tv.x; sy += tv.y;
        }
        float2 o; o.x = sx; o.y = sy;
        *(float2*)(out_c + (size_t)(jj0 + jr) * HH + h2) = o;
    }
}

extern "C" void kernel_launch(void* const* d_in, const int* in_sizes, int n_in,
                              void* d_out, int out_size, void* d_ws, size_t ws_size,
                              hipStream_t stream) {
    const float* enc = (const float*)d_in[0];
    const float* dec = (const float*)d_in[1];
    const float* Wa  = (const float*)d_in[2];
    const float* Ua  = (const float*)d_in[3];
    const float* Va  = (const float*)d_in[4];

    float* W4  = (float*)d_ws;                        // exp2-domain, interleaved (4MB)
    float* Uhe = W4 + (size_t)BB * HH * TE;           // exp2-domain, B*TD*H (2MB)
    unsigned short* Wth = (unsigned short*)(Uhe + (size_t)BB * TD * HH); // W^T hi
    unsigned short* Wtl = Wth + 2 * 256 * 256;                           // W^T lo
    float* Ew = (float*)(Wtl + 2 * 256 * 256);        // partial energies, 2 x 4MB

    float* out_c = (float*)d_out;                     // [B,TD,H]
    float* out_e = out_c + (size_t)BB * TD * HH;      // [B,TD,TE]

    k_tw<<<32, 256, 0, stream>>>(Wa, Ua, Wth, Wtl);
    k_pre<<<384, 256, 0, stream>>>(enc, dec, Wth, Wtl, W4, Uhe);
    k_energy<<<2048, 256, 0, stream>>>(W4, Uhe, Va, Ew);
    k_soft<<<BB * TD / 4, 512, 0, stream>>>(enc, Ew, out_c, out_e);
}

// Round 7
// 107.788 us; speedup vs baseline: 1.1029x; 1.1029x over previous
//
#include <hip/hip_runtime.h>

// Bahdanau additive attention: B=8, TE=512, TD=256, H=256, fp32.
//   We = enc @ W_a; Uh = dec @ U_a
//   e[b,j,i] = softmax_i( sum_h V[h]*tanh(We[b,i,h]+Uh[b,j,h]) )
//   c[b,j,h] = sum_i e[b,j,i]*enc[b,i,h]
// d_out = [c (B*TD*H)] ++ [e (B*TD*TE)]
//
// R15 (this round): CONSOLIDATION. Phase-A scheduling is closed (R10-R14:
// barriers/prefetch/SMEM-vs-LDS/occupancy all null-to-negative). The
// verified cheap lever is kernel count: R10 showed one extra dependent
// launch costs ~3-5us in this harness. So: revert to the best measured
// config (R11 fused k_attn, byte-identical) and FUSE k_tw into k_pre --
// each chunk stages its 32k x 64h fp32 W-slice through LDS T[32][66],
// re-reads transposed, converts to bf16 hi/lo, writes the same
// At_h/At_l[64][40] layout (3 barriers/chunk). Bit-identical values ->
// absmax must stay 0.0004882812. Two kernels total.
// R11 keeps: fused k_attn with 2-deep named-reg prefetch (w4, enc).
// R9 keeps: split-bf16 MFMA GEMM (C = Ah*Bh + Ah*Bl + Al*Bh).
// R8 keeps: 4-way rcp batching. R7 keeps: XCD swizzle, W4 layout.

#define BB 8
#define TE 512
#define TD 256
#define HH 256

#define EXP2F(x) __builtin_amdgcn_exp2f(x)
#define RCPF(x)  __builtin_amdgcn_rcpf(x)
#define KSCALE   2.8853900817779268f    // 2*log2(e)
#define NSC      (-2.8853900817779268f) // -2*log2(e)

typedef __attribute__((ext_vector_type(8))) short short8_t;  // 8 bf16 = 4 VGPR
typedef __attribute__((ext_vector_type(4))) float f32x4;     // MFMA acc

__device__ __forceinline__ unsigned short f2bf(float x) {
    unsigned int u = __float_as_uint(x);
    return (unsigned short)((u + 0x7FFFu + ((u >> 16) & 1u)) >> 16);  // RNE
}
__device__ __forceinline__ float bf2f(unsigned short h) {
    return __uint_as_float(((unsigned int)h) << 16);
}

// ---------------------------------------------------------------------------
// k_pre (R15): split-bf16 MFMA GEMM over X = [enc; dec], D[h][i], with the
// weight transpose+split FUSED into the per-chunk staging (k_tw removed).
// Tile: 64h x 64i, 384 blocks, 4 waves, wave -> 32x32 (2x2 frags of 16x16),
// K-chunks of 32. Per chunk:
//   B1; write Xs (bf16 hi/lo of X) + T[32][66] (fp32 W rows, padded);
//   B2; read T transposed (2-way-conflict scalar reads), convert to bf16
//       hi/lo, write At_h/At_l[64][40] (same layout the MFMA phase always
//       used); prefetch next chunk's X+W; B3; MFMA.
// Fragment layouts (m89-verified):
//   A/B frags: row/col = l&15, k-octet = (l>>4)*8; D: col=l&15, row=(l>>4)*4+reg.
// ---------------------------------------------------------------------------
__global__ __launch_bounds__(256) void k_pre(
    const float* __restrict__ enc, const float* __restrict__ dec,
    const float* __restrict__ Wa,  const float* __restrict__ Ua,
    float* __restrict__ W4, float* __restrict__ Uhe)
{
    const int t  = threadIdx.x;
    const int it = blockIdx.x >> 2;       // 0..95  (i-tile)
    const int ht = blockIdx.x & 3;        // 0..3   (h-tile)
    const int i0 = it * 64;
    const int h0 = ht * 64;
    const bool is_enc = (i0 < BB * TE);   // < 4096
    const float* X  = is_enc ? (enc + (size_t)i0 * HH)
                             : (dec + (size_t)(i0 - BB * TE) * HH);
    const float* Wg = is_enc ? Wa : Ua;

    __shared__ unsigned short At_h[64][40], At_l[64][40];
    __shared__ unsigned short Xs_h[64][40], Xs_l[64][40];
    __shared__ float T[32][66];           // fp32 W chunk, pad 66 (b64-aligned)

    const int sr = t >> 2;                // X staging row / At pass-2 h (0..63)
    const int sq = (t & 3) * 8;           // k-octet (0,8,16,24)
    const int kr = t >> 3;                // W load k-row (0..31)
    const int hc = (t & 7) * 8;           // W load h-base (0..56)

    const int wv = t >> 6, l = t & 63;
    const int wh = (wv & 1) * 32;
    const int wi = (wv >> 1) * 32;
    const int fr = l & 15;
    const int fk = (l >> 4) * 8;
    const int rq = l >> 4;                // D row-quad

    f32x4 acc[2][2];
    #pragma unroll
    for (int a0 = 0; a0 < 2; a0++)
        #pragma unroll
        for (int a1 = 0; a1 < 2; a1++)
            acc[a0][a1] = (f32x4){0.f, 0.f, 0.f, 0.f};

    // prologue: chunk 0 loads (X fp32, W fp32)
    float4 x0  = *(const float4*)(X + (size_t)sr * HH + sq);
    float4 x1  = *(const float4*)(X + (size_t)sr * HH + sq + 4);
    float4 wf0 = *(const float4*)(Wg + (size_t)kr * HH + h0 + hc);
    float4 wf1 = *(const float4*)(Wg + (size_t)kr * HH + h0 + hc + 4);

    #pragma unroll
    for (int c = 0; c < 8; c++) {
        // split current X regs into bf16 hi/lo (exact residual, RNE)
        short8_t xh, xl;
        {
            unsigned short h;
            h = f2bf(x0.x); xh[0] = (short)h; xl[0] = (short)f2bf(x0.x - bf2f(h));
            h = f2bf(x0.y); xh[1] = (short)h; xl[1] = (short)f2bf(x0.y - bf2f(h));
            h = f2bf(x0.z); xh[2] = (short)h; xl[2] = (short)f2bf(x0.z - bf2f(h));
            h = f2bf(x0.w); xh[3] = (short)h; xl[3] = (short)f2bf(x0.w - bf2f(h));
            h = f2bf(x1.x); xh[4] = (short)h; xl[4] = (short)f2bf(x1.x - bf2f(h));
            h = f2bf(x1.y); xh[5] = (short)h; xl[5] = (short)f2bf(x1.y - bf2f(h));
            h = f2bf(x1.z); xh[6] = (short)h; xl[6] = (short)f2bf(x1.z - bf2f(h));
            h = f2bf(x1.w); xh[7] = (short)h; xl[7] = (short)f2bf(x1.w - bf2f(h));
        }
        __syncthreads();   // B1: prior chunk's MFMA readers done
        *(short8_t*)&Xs_h[sr][sq] = xh;
        *(short8_t*)&Xs_l[sr][sq] = xl;
        {   // stage fp32 W rows into T (b64 writes; row stride 66 keeps align)
            float2 a, b;
            a.x = wf0.x; a.y = wf0.y; b.x = wf0.z; b.y = wf0.w;
            *(float2*)&T[kr][hc]     = a;
            *(float2*)&T[kr][hc + 2] = b;
            a.x = wf1.x; a.y = wf1.y; b.x = wf1.z; b.y = wf1.w;
            *(float2*)&T[kr][hc + 4] = a;
            *(float2*)&T[kr][hc + 6] = b;
        }
        __syncthreads();   // B2: T + Xs ready
        {   // transposed read + split -> At (same layout/values as old k_tw)
            short8_t ah_, al_;
            #pragma unroll
            for (int e = 0; e < 8; e++) {
                float f = T[sq + e][sr];
                unsigned short h = f2bf(f);
                ah_[e] = (short)h;
                al_[e] = (short)f2bf(f - bf2f(h));
            }
            *(short8_t*)&At_h[sr][sq] = ah_;
            *(short8_t*)&At_l[sr][sq] = al_;
        }
        if (c < 7) {       // prefetch next chunk while this one computes
            const int kc = (c + 1) * 32;
            x0  = *(const float4*)(X + (size_t)sr * HH + kc + sq);
            x1  = *(const float4*)(X + (size_t)sr * HH + kc + sq + 4);
            wf0 = *(const float4*)(Wg + (size_t)(kc + kr) * HH + h0 + hc);
            wf1 = *(const float4*)(Wg + (size_t)(kc + kr) * HH + h0 + hc + 4);
        }
        __syncthreads();   // B3: At ready
        #pragma unroll
        for (int fm = 0; fm < 2; fm++) {
            short8_t a_h = *(const short8_t*)&At_h[wh + 16 * fm + fr][fk];
            short8_t a_l = *(const short8_t*)&At_l[wh + 16 * fm + fr][fk];
            #pragma unroll
            for (int fn = 0; fn < 2; fn++) {
                short8_t b_h = *(const short8_t*)&Xs_h[wi + 16 * fn + fr][fk];
                short8_t b_l = *(const short8_t*)&Xs_l[wi + 16 * fn + fr][fk];
                acc[fm][fn] = __builtin_amdgcn_mfma_f32_16x16x32_bf16(a_h, b_h, acc[fm][fn], 0, 0, 0);
                acc[fm][fn] = __builtin_amdgcn_mfma_f32_16x16x32_bf16(a_h, b_l, acc[fm][fn], 0, 0, 0);
                acc[fm][fn] = __builtin_amdgcn_mfma_f32_16x16x32_bf16(a_l, b_h, acc[fm][fn], 0, 0, 0);
            }
        }
    }

    #pragma unroll
    for (int fm = 0; fm < 2; fm++) {
        #pragma unroll
        for (int fn = 0; fn < 2; fn++) {
            f32x4 v = acc[fm][fn];
            float4 o;
            o.x = EXP2F(v[0] * KSCALE);
            o.y = EXP2F(v[1] * KSCALE);
            o.z = EXP2F(v[2] * KSCALE);
            o.w = EXP2F(v[3] * KSCALE);
            const int ig = i0 + wi + 16 * fn + fr;      // global concat row
            const int hb = h0 + wh + 16 * fm + rq * 4;  // 4 consecutive h
            if (is_enc) {
                const int b  = ig >> 9;                 // 512 enc rows per batch
                const int ib = ig & 511;
                const int hq = hb >> 2;
                *(float4*)(W4 + (((size_t)b * 64 + hq) * TE + ib) * 4) = o;
            } else {
                const int j = ig - BB * TE;             // global dec row
                *(float4*)(Uhe + (size_t)j * HH + hb) = o;
            }
        }
    }
}

// ---------------------------------------------------------------------------
// k_attn (R11, byte-identical — best measured): 512 threads = 8 waves;
// block owns 4 consecutive j's of ONE batch, batch = blockIdx&7 (XCD-local).
// Phase A: wave w -> i = 64w+lane; 2-deep named-reg prefetch of the w4
// stream. Softmax: waves 0-3. Phase B: 2-deep prefetch on the enc stream.
// ---------------------------------------------------------------------------
__global__ __launch_bounds__(512) void k_attn(
    const float* __restrict__ enc, const float* __restrict__ W4,
    const float* __restrict__ Uhe, const float* __restrict__ Va,
    float* __restrict__ out_c, float* __restrict__ out_e)
{
    const int wv = threadIdx.x >> 6, lane = threadIdx.x & 63;
    const int b   = blockIdx.x & 7;           // XCD-local batch
    const int j0  = (blockIdx.x >> 3) * 4;    // 64 j-groups per batch
    const int jj0 = b * TD + j0;              // block-uniform

    __shared__ float sP[4][TE];      // 8 KB: energies -> probabilities
    __shared__ float sR[8][4][HH];   // 32 KB: phase-B partials

    const int i = (wv << 6) + lane;
    const float* wp = W4 + ((size_t)b * 64 * TE + i) * 4;
    const float* ua = Uhe + (size_t)jj0 * HH;   // block-uniform -> s_load
    const float* va = Va;                        // uniform

    float a0 = 0.f, a1 = 0.f, a2 = 0.f, a3 = 0.f;

    // 4-way batched reciprocal:
    //   sum_k v_k/A_k = (nAB*dCD + nCD*dAB) / (dAB*dCD),
    //   A=1+wx*ux.., dAB=A*B, nAB=vx*B+vy*A, ...
#define QSTEP(ACC, U)                                                     \
    {                                                                     \
        float A_ = fmaf(w4.x, (U).x, 1.f);                                \
        float B_ = fmaf(w4.y, (U).y, 1.f);                                \
        float C_ = fmaf(w4.z, (U).z, 1.f);                                \
        float D_ = fmaf(w4.w, (U).w, 1.f);                                \
        float dAB = A_ * B_, dCD = C_ * D_;                               \
        float nAB = fmaf(v4.x, B_, v4.y * A_);                            \
        float nCD = fmaf(v4.z, D_, v4.w * C_);                            \
        float num = fmaf(nAB, dCD, nCD * dAB);                            \
        ACC = fmaf(num, RCPF(dAB * dCD), ACC);                            \
    }

#define ASTEP(Q, W4V)                                                     \
    {                                                                     \
        float4 w4 = W4V;                                                  \
        float4 v4 = *(const float4*)(va + 4 * (Q));                       \
        float4 u0 = *(const float4*)(ua + 4 * (Q));                       \
        float4 u1 = *(const float4*)(ua + HH + 4 * (Q));                  \
        float4 u2 = *(const float4*)(ua + 2 * HH + 4 * (Q));              \
        float4 u3 = *(const float4*)(ua + 3 * HH + 4 * (Q));              \
        QSTEP(a0, u0)                                                     \
        QSTEP(a1, u1)                                                     \
        QSTEP(a2, u2)                                                     \
        QSTEP(a3, u3)                                                     \
    }

    // 2-deep software pipeline on the per-lane w4 stream
    float4 wA = *(const float4*)(wp);
    float4 wB = *(const float4*)(wp + (size_t)TE * 4);
    for (int q = 0; q < 64; q += 2) {
        float4 wC = *(const float4*)(wp + (size_t)(q + 2) * TE * 4);
        float4 wD = *(const float4*)(wp + (size_t)(q + 3) * TE * 4);
        ASTEP(q, wA)
        ASTEP(q + 1, wB)
        wA = wC; wB = wD;
    }
#undef ASTEP
#undef QSTEP

    // conflict-free b32 writes (lane-stride 4B), energies in log2 domain
    sP[0][i] = NSC * a0;
    sP[1][i] = NSC * a1;
    sP[2][i] = NSC * a2;
    sP[3][i] = NSC * a3;
    __syncthreads();

    // ---- softmax: wave w in 0..3 handles j0+w ----------------------------
    if (wv < 4) {
        float ev[8];
        float m = -3.0e38f;
        #pragma unroll
        for (int k = 0; k < 8; k++) {
            ev[k] = sP[wv][lane + 64 * k];
            m = fmaxf(m, ev[k]);
        }
        #pragma unroll
        for (int off = 32; off; off >>= 1) m = fmaxf(m, __shfl_xor(m, off, 64));
        float s = 0.f;
        #pragma unroll
        for (int k = 0; k < 8; k++) { ev[k] = EXP2F(ev[k] - m); s += ev[k]; }
        #pragma unroll
        for (int off = 32; off; off >>= 1) s += __shfl_xor(s, off, 64);
        float rs = RCPF(s);
        float* oe = out_e + (size_t)(jj0 + wv) * TE;
        #pragma unroll
        for (int k = 0; k < 8; k++) {
            float p = ev[k] * rs;
            sP[wv][lane + 64 * k] = p;
            oe[lane + 64 * k] = p;
        }
    }
    __syncthreads();

    // ---- Phase B: wave w -> i in [64w, 64w+64), all 4 j ------------------
    const int ib = wv << 6;
    const float* eb = enc + ((size_t)b * TE + ib) * HH + 4 * lane;
    float4 c0 = {0,0,0,0}, c1 = {0,0,0,0}, c2 = {0,0,0,0}, c3 = {0,0,0,0};

#define BSTEP(K, QV)                                                      \
    {                                                                     \
        float p0 = sP[0][ib + (K)];                                       \
        float p1 = sP[1][ib + (K)];                                       \
        float p2 = sP[2][ib + (K)];                                       \
        float p3 = sP[3][ib + (K)];                                       \
        float4 q = QV;                                                    \
        c0.x = fmaf(p0, q.x, c0.x); c0.y = fmaf(p0, q.y, c0.y);           \
        c0.z = fmaf(p0, q.z, c0.z); c0.w = fmaf(p0, q.w, c0.w);           \
        c1.x = fmaf(p1, q.x, c1.x); c1.y = fmaf(p1, q.y, c1.y);           \
        c1.z = fmaf(p1, q.z, c1.z); c1.w = fmaf(p1, q.w, c1.w);           \
        c2.x = fmaf(p2, q.x, c2.x); c2.y = fmaf(p2, q.y, c2.y);           \
        c2.z = fmaf(p2, q.z, c2.z); c2.w = fmaf(p2, q.w, c2.w);           \
        c3.x = fmaf(p3, q.x, c3.x); c3.y = fmaf(p3, q.y, c3.y);           \
        c3.z = fmaf(p3, q.z, c3.z); c3.w = fmaf(p3, q.w, c3.w);           \
    }

    // 2-deep software pipeline on the per-lane enc stream (tail clamped:
    // enc is an input buffer, no OOB reads allowed)
    float4 qA = *(const float4*)(eb);
    float4 qB = *(const float4*)(eb + (size_t)HH);
    for (int k = 0; k < 64; k += 2) {
        const int k2 = (k + 2 < 64) ? k + 2 : 62;
        const int k3 = (k + 3 < 64) ? k + 3 : 63;
        float4 qC = *(const float4*)(eb + (size_t)k2 * HH);
        float4 qD = *(const float4*)(eb + (size_t)k3 * HH);
        BSTEP(k, qA)
        BSTEP(k + 1, qB)
        qA = qC; qB = qD;
    }
#undef BSTEP

    *(float4*)&sR[wv][0][4 * lane] = c0;
    *(float4*)&sR[wv][1][4 * lane] = c1;
    *(float4*)&sR[wv][2][4 * lane] = c2;
    *(float4*)&sR[wv][3][4 * lane] = c3;
    __syncthreads();

    // ---- final reduce: wave w -> (j = w&3, h-half = w>>2) ----------------
    {
        const int jr = wv & 3;
        const int h2 = (wv >> 2) * 128 + 2 * lane;
        float sx = 0.f, sy = 0.f;
        #pragma unroll
        for (int ww = 0; ww < 8; ww++) {
            float2 tv = *(const float2*)&sR[ww][jr][h2];
            sx += tv.x; sy += tv.y;
        }
        float2 o; o.x = sx; o.y = sy;
        *(float2*)(out_c + (size_t)(jj0 + jr) * HH + h2) = o;
    }
}

extern "C" void kernel_launch(void* const* d_in, const int* in_sizes, int n_in,
                              void* d_out, int out_size, void* d_ws, size_t ws_size,
                              hipStream_t stream) {
    const float* enc = (const float*)d_in[0];
    const float* dec = (const float*)d_in[1];
    const float* Wa  = (const float*)d_in[2];
    const float* Ua  = (const float*)d_in[3];
    const float* Va  = (const float*)d_in[4];

    float* W4  = (float*)d_ws;                        // exp2-domain, interleaved (4MB)
    float* Uhe = W4 + (size_t)BB * HH * TE;           // exp2-domain, B*TD*H (2MB)

    float* out_c = (float*)d_out;                     // [B,TD,H]
    float* out_e = out_c + (size_t)BB * TD * HH;      // [B,TD,TE]

    k_pre<<<384, 256, 0, stream>>>(enc, dec, Wa, Ua, W4, Uhe);
    k_attn<<<BB * TD / 4, 512, 0, stream>>>(enc, W4, Uhe, Va, out_c, out_e);
}

// Round 8
// 107.156 us; speedup vs baseline: 1.1094x; 1.0059x over previous
//
#include <hip/hip_runtime.h>

// Bahdanau additive attention: B=8, TE=512, TD=256, H=256, fp32.
//   We = enc @ W_a; Uh = dec @ U_a
//   e[b,j,i] = softmax_i( sum_h V[h]*tanh(We[b,i,h]+Uh[b,j,h]) )
//   c[b,j,h] = sum_i e[b,j,i]*enc[b,i,h]
// d_out = [c (B*TD*H)] ++ [e (B*TD*TE)]
//
// R16 (this round): PACKED-FP32 phase A. Scheduling levers are exhausted
// (R10-R14 all null); the untouched lever is instruction count. QSTEP is
// identical for every q -> pack ACROSS q-pairs (q, q+4) so every op in the
// chain becomes one v_pk_fma_f32/v_pk_mul_f32 (full-rate on CDNA): 52
// scalar VALU issues per q-step -> 26 packed. rcp count unchanged.
// Operand streams are stored pair-interleaved to make packing free:
//   - W8[b][pair][i][8] and Uhe2[j][pair*8]: k_pre's fm=0/fm=1 D-fragments
//     ARE h-quads (q,q+4), so its epilogue emits the interleaved octets
//     with the same number of dwordx4 stores.
//   - Va: interleaved once per block into LDS (1 KB).
// Accumulators are f32x2 (lo+hi summed at end) -> summation order changes,
// absmax expected ~5e-4 still.
// R15 keeps: 2-kernel config, fused weight-transpose in k_pre.
// R11 keeps: 2-deep named-reg prefetch (w-stream, enc-stream).
// R9 keeps: split-bf16 MFMA GEMM. R8: 4-way rcp batching. R7: XCD swizzle.

#define BB 8
#define TE 512
#define TD 256
#define HH 256

#define EXP2F(x) __builtin_amdgcn_exp2f(x)
#define RCPF(x)  __builtin_amdgcn_rcpf(x)
#define KSCALE   2.8853900817779268f    // 2*log2(e)
#define NSC      (-2.8853900817779268f) // -2*log2(e)

typedef __attribute__((ext_vector_type(8))) short short8_t;  // 8 bf16 = 4 VGPR
typedef __attribute__((ext_vector_type(4))) float f32x4;     // MFMA acc
typedef __attribute__((ext_vector_type(2))) float f32x2;     // packed fp32
#define PKFMA(a, b, c) __builtin_elementwise_fma((a), (b), (c))

__device__ __forceinline__ unsigned short f2bf(float x) {
    unsigned int u = __float_as_uint(x);
    return (unsigned short)((u + 0x7FFFu + ((u >> 16) & 1u)) >> 16);  // RNE
}
__device__ __forceinline__ float bf2f(unsigned short h) {
    return __uint_as_float(((unsigned int)h) << 16);
}

// ---------------------------------------------------------------------------
// k_pre (R16): split-bf16 MFMA GEMM over X = [enc; dec], D[h][i], fused
// weight transpose (R15). NEW epilogue: the fm=0 / fm=1 fragments (h-quads
// Q0 and Q0+4) are interleaved into pair-octets:
//   {e0.x,e1.x,e0.y,e1.y} {e0.z,e1.z,e0.w,e1.w}  (two dwordx4 stores)
// enc -> W8[b][p][i][8],  dec -> Uhe2[j][p*8],  p = ((Q0>>3)<<2)|(Q0&3).
// ---------------------------------------------------------------------------
__global__ __launch_bounds__(256) void k_pre(
    const float* __restrict__ enc, const float* __restrict__ dec,
    const float* __restrict__ Wa,  const float* __restrict__ Ua,
    float* __restrict__ W8, float* __restrict__ Uhe2)
{
    const int t  = threadIdx.x;
    const int it = blockIdx.x >> 2;       // 0..95  (i-tile)
    const int ht = blockIdx.x & 3;        // 0..3   (h-tile)
    const int i0 = it * 64;
    const int h0 = ht * 64;
    const bool is_enc = (i0 < BB * TE);   // < 4096
    const float* X  = is_enc ? (enc + (size_t)i0 * HH)
                             : (dec + (size_t)(i0 - BB * TE) * HH);
    const float* Wg = is_enc ? Wa : Ua;

    __shared__ unsigned short At_h[64][40], At_l[64][40];
    __shared__ unsigned short Xs_h[64][40], Xs_l[64][40];
    __shared__ float T[32][66];           // fp32 W chunk, padded

    const int sr = t >> 2;                // X staging row / At pass-2 h (0..63)
    const int sq = (t & 3) * 8;           // k-octet (0,8,16,24)
    const int kr = t >> 3;                // W load k-row (0..31)
    const int hc = (t & 7) * 8;           // W load h-base (0..56)

    const int wv = t >> 6, l = t & 63;
    const int wh = (wv & 1) * 32;
    const int wi = (wv >> 1) * 32;
    const int fr = l & 15;
    const int fk = (l >> 4) * 8;
    const int rq = l >> 4;                // D row-quad

    f32x4 acc[2][2];
    #pragma unroll
    for (int a0 = 0; a0 < 2; a0++)
        #pragma unroll
        for (int a1 = 0; a1 < 2; a1++)
            acc[a0][a1] = (f32x4){0.f, 0.f, 0.f, 0.f};

    float4 x0  = *(const float4*)(X + (size_t)sr * HH + sq);
    float4 x1  = *(const float4*)(X + (size_t)sr * HH + sq + 4);
    float4 wf0 = *(const float4*)(Wg + (size_t)kr * HH + h0 + hc);
    float4 wf1 = *(const float4*)(Wg + (size_t)kr * HH + h0 + hc + 4);

    #pragma unroll
    for (int c = 0; c < 8; c++) {
        short8_t xh, xl;
        {
            unsigned short h;
            h = f2bf(x0.x); xh[0] = (short)h; xl[0] = (short)f2bf(x0.x - bf2f(h));
            h = f2bf(x0.y); xh[1] = (short)h; xl[1] = (short)f2bf(x0.y - bf2f(h));
            h = f2bf(x0.z); xh[2] = (short)h; xl[2] = (short)f2bf(x0.z - bf2f(h));
            h = f2bf(x0.w); xh[3] = (short)h; xl[3] = (short)f2bf(x0.w - bf2f(h));
            h = f2bf(x1.x); xh[4] = (short)h; xl[4] = (short)f2bf(x1.x - bf2f(h));
            h = f2bf(x1.y); xh[5] = (short)h; xl[5] = (short)f2bf(x1.y - bf2f(h));
            h = f2bf(x1.z); xh[6] = (short)h; xl[6] = (short)f2bf(x1.z - bf2f(h));
            h = f2bf(x1.w); xh[7] = (short)h; xl[7] = (short)f2bf(x1.w - bf2f(h));
        }
        __syncthreads();   // B1: prior chunk's MFMA readers done
        *(short8_t*)&Xs_h[sr][sq] = xh;
        *(short8_t*)&Xs_l[sr][sq] = xl;
        {
            float2 a, b;
            a.x = wf0.x; a.y = wf0.y; b.x = wf0.z; b.y = wf0.w;
            *(float2*)&T[kr][hc]     = a;
            *(float2*)&T[kr][hc + 2] = b;
            a.x = wf1.x; a.y = wf1.y; b.x = wf1.z; b.y = wf1.w;
            *(float2*)&T[kr][hc + 4] = a;
            *(float2*)&T[kr][hc + 6] = b;
        }
        __syncthreads();   // B2: T + Xs ready
        {
            short8_t ah_, al_;
            #pragma unroll
            for (int e = 0; e < 8; e++) {
                float f = T[sq + e][sr];
                unsigned short h = f2bf(f);
                ah_[e] = (short)h;
                al_[e] = (short)f2bf(f - bf2f(h));
            }
            *(short8_t*)&At_h[sr][sq] = ah_;
            *(short8_t*)&At_l[sr][sq] = al_;
        }
        if (c < 7) {
            const int kc = (c + 1) * 32;
            x0  = *(const float4*)(X + (size_t)sr * HH + kc + sq);
            x1  = *(const float4*)(X + (size_t)sr * HH + kc + sq + 4);
            wf0 = *(const float4*)(Wg + (size_t)(kc + kr) * HH + h0 + hc);
            wf1 = *(const float4*)(Wg + (size_t)(kc + kr) * HH + h0 + hc + 4);
        }
        __syncthreads();   // B3: At ready
        #pragma unroll
        for (int fm = 0; fm < 2; fm++) {
            short8_t a_h = *(const short8_t*)&At_h[wh + 16 * fm + fr][fk];
            short8_t a_l = *(const short8_t*)&At_l[wh + 16 * fm + fr][fk];
            #pragma unroll
            for (int fn = 0; fn < 2; fn++) {
                short8_t b_h = *(const short8_t*)&Xs_h[wi + 16 * fn + fr][fk];
                short8_t b_l = *(const short8_t*)&Xs_l[wi + 16 * fn + fr][fk];
                acc[fm][fn] = __builtin_amdgcn_mfma_f32_16x16x32_bf16(a_h, b_h, acc[fm][fn], 0, 0, 0);
                acc[fm][fn] = __builtin_amdgcn_mfma_f32_16x16x32_bf16(a_h, b_l, acc[fm][fn], 0, 0, 0);
                acc[fm][fn] = __builtin_amdgcn_mfma_f32_16x16x32_bf16(a_l, b_h, acc[fm][fn], 0, 0, 0);
            }
        }
    }

    // ---- epilogue: pair-interleave fm=0/fm=1 (h-quads Q0, Q0+4) ----------
    const int Q0 = (h0 + wh + rq * 4) >> 2;       // Q0 mod 8 in 0..3
    const int p  = ((Q0 >> 3) << 2) | (Q0 & 3);   // pair index 0..31
    #pragma unroll
    for (int fn = 0; fn < 2; fn++) {
        f32x4 v0 = acc[0][fn], v1 = acc[1][fn];
        float4 e0, e1;
        e0.x = EXP2F(v0[0] * KSCALE); e0.y = EXP2F(v0[1] * KSCALE);
        e0.z = EXP2F(v0[2] * KSCALE); e0.w = EXP2F(v0[3] * KSCALE);
        e1.x = EXP2F(v1[0] * KSCALE); e1.y = EXP2F(v1[1] * KSCALE);
        e1.z = EXP2F(v1[2] * KSCALE); e1.w = EXP2F(v1[3] * KSCALE);
        float4 lo, hi;
        lo.x = e0.x; lo.y = e1.x; lo.z = e0.y; lo.w = e1.y;
        hi.x = e0.z; hi.y = e1.z; hi.z = e0.w; hi.w = e1.w;
        const int ig = i0 + wi + 16 * fn + fr;    // global concat row
        if (is_enc) {
            const int b  = ig >> 9;
            const int ib = ig & 511;
            float* dst = W8 + (((size_t)b * 32 + p) * TE + ib) * 8;
            *(float4*)dst       = lo;
            *(float4*)(dst + 4) = hi;
        } else {
            const int j = ig - BB * TE;
            float* dst = Uhe2 + (size_t)j * HH + p * 8;
            *(float4*)dst       = lo;
            *(float4*)(dst + 4) = hi;
        }
    }
}

// ---------------------------------------------------------------------------
// k_attn (R16): phase A in packed fp32 over q-pairs (q, q+4).
// 512 threads = 8 waves; block owns 4 consecutive j's of ONE batch,
// batch = blockIdx&7 (XCD-local). Per pair-iteration per j: 13 pk-ops +
// 2 rcp (vs 26 scalar + 2 rcp). w-stream: 2-deep named-reg prefetch.
// Softmax and phase B unchanged from R11.
// ---------------------------------------------------------------------------
__global__ __launch_bounds__(512) void k_attn(
    const float* __restrict__ enc, const float* __restrict__ W8,
    const float* __restrict__ Uhe2, const float* __restrict__ Va,
    float* __restrict__ out_c, float* __restrict__ out_e)
{
    const int wv = threadIdx.x >> 6, lane = threadIdx.x & 63;
    const int b   = blockIdx.x & 7;           // XCD-local batch
    const int j0  = (blockIdx.x >> 3) * 4;    // 64 j-groups per batch
    const int jj0 = b * TD + j0;              // block-uniform

    __shared__ float sP[4][TE];      // 8 KB: energies -> probabilities
    __shared__ float sR[8][4][HH];   // 32 KB: phase-B partials
    __shared__ float sVi[32][8];     // 1 KB: pair-interleaved Va

    // stage interleaved Va: sVi[p][2e+par] = Va[32*(p>>2)+4*(p&3)+16*par+e]
    if (threadIdx.x < 256) {
        const int p = threadIdx.x >> 3, r = threadIdx.x & 7;
        sVi[p][r] = Va[32 * (p >> 2) + 4 * (p & 3) + 16 * (r & 1) + (r >> 1)];
    }
    __syncthreads();

    const int i = (wv << 6) + lane;
    const float* wp = W8 + ((size_t)b * 32 * TE + i) * 8;
    const float* ua = Uhe2 + (size_t)jj0 * HH;   // block-uniform -> s_load

    f32x2 acc[4];
    #pragma unroll
    for (int j = 0; j < 4; j++) acc[j] = (f32x2){0.f, 0.f};
    const f32x2 one = (f32x2){1.f, 1.f};

    // depth-1 prefetch on the per-lane w-octet stream (32B/iter)
    float4 wl  = *(const float4*)(wp);
    float4 wh_ = *(const float4*)(wp + 4);
    for (int p = 0; p < 32; p++) {
        const int pn = (p < 31) ? p + 1 : 31;
        float4 nl = *(const float4*)(wp + (size_t)pn * TE * 8);
        float4 nh = *(const float4*)(wp + (size_t)pn * TE * 8 + 4);
        float4 vlo = *(const float4*)&sVi[p][0];
        float4 vhi = *(const float4*)&sVi[p][4];
        f32x2 wx = {wl.x, wl.y},   wy = {wl.z, wl.w};
        f32x2 wz = {wh_.x, wh_.y}, ww = {wh_.z, wh_.w};
        f32x2 vx = {vlo.x, vlo.y}, vy = {vlo.z, vlo.w};
        f32x2 vz = {vhi.x, vhi.y}, vw = {vhi.z, vhi.w};
        #pragma unroll
        for (int j = 0; j < 4; j++) {
            float4 ulo = *(const float4*)(ua + j * HH + p * 8);
            float4 uhi = *(const float4*)(ua + j * HH + p * 8 + 4);
            f32x2 ux = {ulo.x, ulo.y}, uy = {ulo.z, ulo.w};
            f32x2 uz = {uhi.x, uhi.y}, uw = {uhi.z, uhi.w};
            f32x2 A_ = PKFMA(wx, ux, one);
            f32x2 B_ = PKFMA(wy, uy, one);
            f32x2 C_ = PKFMA(wz, uz, one);
            f32x2 D_ = PKFMA(ww, uw, one);
            f32x2 dAB = A_ * B_, dCD = C_ * D_;
            f32x2 nAB = PKFMA(vx, B_, vy * A_);
            f32x2 nCD = PKFMA(vz, D_, vw * C_);
            f32x2 num = PKFMA(nAB, dCD, nCD * dAB);
            f32x2 den = dAB * dCD;
            f32x2 r;
            r.x = RCPF(den.x);
            r.y = RCPF(den.y);
            acc[j] = PKFMA(num, r, acc[j]);
        }
        wl = nl; wh_ = nh;
    }

    // conflict-free b32 writes (lane-stride 4B), energies in log2 domain
    sP[0][i] = NSC * (acc[0].x + acc[0].y);
    sP[1][i] = NSC * (acc[1].x + acc[1].y);
    sP[2][i] = NSC * (acc[2].x + acc[2].y);
    sP[3][i] = NSC * (acc[3].x + acc[3].y);
    __syncthreads();

    // ---- softmax: wave w in 0..3 handles j0+w ----------------------------
    if (wv < 4) {
        float ev[8];
        float m = -3.0e38f;
        #pragma unroll
        for (int k = 0; k < 8; k++) {
            ev[k] = sP[wv][lane + 64 * k];
            m = fmaxf(m, ev[k]);
        }
        #pragma unroll
        for (int off = 32; off; off >>= 1) m = fmaxf(m, __shfl_xor(m, off, 64));
        float s = 0.f;
        #pragma unroll
        for (int k = 0; k < 8; k++) { ev[k] = EXP2F(ev[k] - m); s += ev[k]; }
        #pragma unroll
        for (int off = 32; off; off >>= 1) s += __shfl_xor(s, off, 64);
        float rs = RCPF(s);
        float* oe = out_e + (size_t)(jj0 + wv) * TE;
        #pragma unroll
        for (int k = 0; k < 8; k++) {
            float p = ev[k] * rs;
            sP[wv][lane + 64 * k] = p;
            oe[lane + 64 * k] = p;
        }
    }
    __syncthreads();

    // ---- Phase B: wave w -> i in [64w, 64w+64), all 4 j ------------------
    const int ib = wv << 6;
    const float* eb = enc + ((size_t)b * TE + ib) * HH + 4 * lane;
    float4 c0 = {0,0,0,0}, c1 = {0,0,0,0}, c2 = {0,0,0,0}, c3 = {0,0,0,0};

#define BSTEP(K, QV)                                                      \
    {                                                                     \
        float p0 = sP[0][ib + (K)];                                       \
        float p1 = sP[1][ib + (K)];                                       \
        float p2 = sP[2][ib + (K)];                                       \
        float p3 = sP[3][ib + (K)];                                       \
        float4 q = QV;                                                    \
        c0.x = fmaf(p0, q.x, c0.x); c0.y = fmaf(p0, q.y, c0.y);           \
        c0.z = fmaf(p0, q.z, c0.z); c0.w = fmaf(p0, q.w, c0.w);           \
        c1.x = fmaf(p1, q.x, c1.x); c1.y = fmaf(p1, q.y, c1.y);           \
        c1.z = fmaf(p1, q.z, c1.z); c1.w = fmaf(p1, q.w, c1.w);           \
        c2.x = fmaf(p2, q.x, c2.x); c2.y = fmaf(p2, q.y, c2.y);           \
        c2.z = fmaf(p2, q.z, c2.z); c2.w = fmaf(p2, q.w, c2.w);           \
        c3.x = fmaf(p3, q.x, c3.x); c3.y = fmaf(p3, q.y, c3.y);           \
        c3.z = fmaf(p3, q.z, c3.z); c3.w = fmaf(p3, q.w, c3.w);           \
    }

    float4 qA = *(const float4*)(eb);
    float4 qB = *(const float4*)(eb + (size_t)HH);
    for (int k = 0; k < 64; k += 2) {
        const int k2 = (k + 2 < 64) ? k + 2 : 62;
        const int k3 = (k + 3 < 64) ? k + 3 : 63;
        float4 qC = *(const float4*)(eb + (size_t)k2 * HH);
        float4 qD = *(const float4*)(eb + (size_t)k3 * HH);
        BSTEP(k, qA)
        BSTEP(k + 1, qB)
        qA = qC; qB = qD;
    }
#undef BSTEP

    *(float4*)&sR[wv][0][4 * lane] = c0;
    *(float4*)&sR[wv][1][4 * lane] = c1;
    *(float4*)&sR[wv][2][4 * lane] = c2;
    *(float4*)&sR[wv][3][4 * lane] = c3;
    __syncthreads();

    // ---- final reduce: wave w -> (j = w&3, h-half = w>>2) ----------------
    {
        const int jr = wv & 3;
        const int h2 = (wv >> 2) * 128 + 2 * lane;
        float sx = 0.f, sy = 0.f;
        #pragma unroll
        for (int ww = 0; ww < 8; ww++) {
            float2 tv = *(const float2*)&sR[ww][jr][h2];
            sx += tv.x; sy += tv.y;
        }
        float2 o; o.x = sx; o.y = sy;
        *(float2*)(out_c + (size_t)(jj0 + jr) * HH + h2) = o;
    }
}

extern "C" void kernel_launch(void* const* d_in, const int* in_sizes, int n_in,
                              void* d_out, int out_size, void* d_ws, size_t ws_size,
                              hipStream_t stream) {
    const float* enc = (const float*)d_in[0];
    const float* dec = (const float*)d_in[1];
    const float* Wa  = (const float*)d_in[2];
    const float* Ua  = (const float*)d_in[3];
    const float* Va  = (const float*)d_in[4];

    float* W8   = (float*)d_ws;                       // exp2-domain, pair-octets (4MB)
    float* Uhe2 = W8 + (size_t)BB * HH * TE;          // exp2-domain, interleaved (2MB)

    float* out_c = (float*)d_out;                     // [B,TD,H]
    float* out_e = out_c + (size_t)BB * TD * HH;      // [B,TD,TE]

    k_pre<<<384, 256, 0, stream>>>(enc, dec, Wa, Ua, W8, Uhe2);
    k_attn<<<BB * TD / 4, 512, 0, stream>>>(enc, W8, Uhe2, Va, out_c, out_e);
}